// Round 2
// baseline (151.235 us; speedup 1.0000x reference)
//
#include <hip/hip_runtime.h>

// GraphProjection, round 5: lane-stride-1 dword mapping, no feature staging.
//
// Round-4 post-mortem: 4B-aligned fx4 stores compile to 4x global_store_dword
// at lane-stride-16B => every store instruction spans 4KB at 25% line
// utilization (plus nt = no-allocate) -> regression.  The invariant that
// matters is lane-consecutive store runs, not vector width.
//
// This version: thread handles one dword per iteration, f = lane-consecutive
// index over the block's 4x960 feature floats.
//   * stores: 64 consecutive dwords per wave-instr = fully coalesced at any
//     byte offset -> the +3 coord offset is irrelevant. No LDS staging at all.
//   * level boundaries (64/192/448) and per-point length (960) are all
//     multiples of 64 -> each wave lies in ONE (point,level): corner pointers
//     + weights are wave-uniform (LDS broadcast reads), and the 4 corner
//     gathers are lane-consecutive scalar loads = coalesced 256B L1/L2 reads
//     (feature maps total ~1.5MB, L2-resident).
//   * zero LDS bank conflicts, one barrier, one code path for main+tail.

#define PTS  4
#define ROWF 963   // 3 coords + 960 samples

__global__ __launch_bounds__(256) void graphproj_kernel(
    const float* __restrict__ coords,
    const float* __restrict__ f1, const float* __restrict__ f2,
    const float* __restrict__ f3, const float* __restrict__ f4,
    float* __restrict__ out, int N)
{
    __shared__ float s_w[PTS][4][4];          // w11,w21,w12,w22
    __shared__ const float* s_q[PTS][4][4];   // corner ptrs

    const int b  = blockIdx.x;
    const int t  = threadIdx.x;
    const int p0 = b * PTS;
    const int npts = min(PTS, N - p0);

    // ---- phase 0: weights + corner pointers (16 lanes) ----
    if (t < 4 * npts) {
        const int pt = t >> 2;
        const int lv = t & 3;
        const int p  = p0 + pt;
        const float X = coords[p * 3 + 0];
        const float Y = coords[p * 3 + 1];
        const float Z = coords[p * 3 + 2];
        float h = 250.0f * (-Y) / (-Z) + 112.0f;
        float w = 250.0f * X / (-Z) + 112.0f;
        h = fminf(fmaxf(h, 0.0f), 223.0f);
        w = fminf(fmaxf(w, 0.0f), 223.0f);

        const int H = (lv == 0) ? 56 : (lv == 1) ? 28 : (lv == 2) ? 14 : 7;
        const int C = (lv == 0) ? 64 : (lv == 1) ? 128 : (lv == 2) ? 256 : 512;
        const float scale = (float)H / 224.0f;   // exact power-of-2 ratio
        const float x = h * scale, y = w * scale;
        const float x1f = floorf(x), x2f = fminf(ceilf(x), (float)(H - 1));
        const float y1f = floorf(y), y2f = fminf(ceilf(y), (float)(H - 1));
        const int xi1 = (int)x1f, xi2 = (int)x2f;
        const int yi1 = (int)y1f, yi2 = (int)y2f;

        s_w[pt][lv][0] = (x2f - x) * (y2f - y);   // w11 -> Q11 (xi1,yi1)
        s_w[pt][lv][1] = (x - x1f) * (y2f - y);   // w21 -> Q21 (xi2,yi1)
        s_w[pt][lv][2] = (x2f - x) * (y - y1f);   // w12 -> Q12 (xi1,yi2)
        s_w[pt][lv][3] = (x - x1f) * (y - y1f);   // w22 -> Q22 (xi2,yi2)

        const float* f = (lv == 0) ? f1 : (lv == 1) ? f2 : (lv == 2) ? f3 : f4;
        s_q[pt][lv][0] = f + (size_t)(xi1 * H + yi1) * C;
        s_q[pt][lv][1] = f + (size_t)(xi2 * H + yi1) * C;
        s_q[pt][lv][2] = f + (size_t)(xi1 * H + yi2) * C;
        s_q[pt][lv][3] = f + (size_t)(xi2 * H + yi2) * C;
    }
    // coords straight to global (cols 0..2 of each row)
    if (t >= 64 && t < 64 + 3 * npts) {
        const int i = t - 64;
        out[(size_t)(p0 + i / 3) * ROWF + (i % 3)] = coords[p0 * 3 + i];
    }
    __syncthreads();

    // ---- main: one dword per lane per iter ----
    // f lane-consecutive over npts*960 feature floats; each wave is entirely
    // within one (pt,lv) when the block is full (960 and all level starts are
    // multiples of 64).
    const int total = npts * 960;
    if (total == PTS * 960) {
        #pragma unroll 3
        for (int k = 0; k < PTS * 960 / 256; ++k) {
            const int f  = t + 256 * k;
            const int pt = f / 960;
            const int c  = f - pt * 960;
            const int lv = (c >= 64) + (c >= 192) + (c >= 448);
            const int cc = c - ((lv == 0) ? 0 : (lv == 1) ? 64 : (lv == 2) ? 192 : 448);
            const float v = s_w[pt][lv][0] * s_q[pt][lv][0][cc]
                          + s_w[pt][lv][1] * s_q[pt][lv][1][cc]
                          + s_w[pt][lv][2] * s_q[pt][lv][2][cc]
                          + s_w[pt][lv][3] * s_q[pt][lv][3][cc];
            out[(size_t)p0 * ROWF + (size_t)pt * ROWF + 3 + c] = v;
        }
    } else {
        for (int f = t; f < total; f += 256) {
            const int pt = f / 960;
            const int c  = f - pt * 960;
            const int lv = (c >= 64) + (c >= 192) + (c >= 448);
            const int cc = c - ((lv == 0) ? 0 : (lv == 1) ? 64 : (lv == 2) ? 192 : 448);
            const float v = s_w[pt][lv][0] * s_q[pt][lv][0][cc]
                          + s_w[pt][lv][1] * s_q[pt][lv][1][cc]
                          + s_w[pt][lv][2] * s_q[pt][lv][2][cc]
                          + s_w[pt][lv][3] * s_q[pt][lv][3][cc];
            out[(size_t)p0 * ROWF + (size_t)pt * ROWF + 3 + c] = v;
        }
    }
}

extern "C" void kernel_launch(void* const* d_in, const int* in_sizes, int n_in,
                              void* d_out, int out_size, void* d_ws, size_t ws_size,
                              hipStream_t stream) {
    const float* coords = (const float*)d_in[0];
    const float* f1 = (const float*)d_in[1];
    const float* f2 = (const float*)d_in[2];
    const float* f3 = (const float*)d_in[3];
    const float* f4 = (const float*)d_in[4];
    float* out = (float*)d_out;
    const int N = in_sizes[0] / 3;

    const int blocks = (N + PTS - 1) / PTS;
    graphproj_kernel<<<blocks, 256, 0, stream>>>(coords, f1, f2, f3, f4, out, N);
}

// Round 3
// 86.308 us; speedup vs baseline: 1.7523x; 1.7523x over previous
//
#include <hip/hip_runtime.h>

// GraphProjection, round 6: round-3 staging structure, LDS-pipe cost cut.
//
// Theory: round 3 (76.9-80us) was LDS-pipe-bound: ~1860 LDS cycles/block
// (x98 blocks/CU = 76us @2.4GHz, matches measurement).  Biggest item: the
// 4 scalar ds_writes at lane-stride-16B = 8-way bank conflict (~2.94x).
// A bits-2..3 XOR swizzle can't fix stride-4-dword scalars (stays in the
// mod-4 bank coset), so use an IN-GROUP ROTATION swizzle:
//   logical dword a -> physical (a & ~3) | ((a&3) + f(g)) & 3,  g = a>>2,
//   f(g) = (g + (g>>3)) & 3.
// For a fixed blended component across 64 lanes (addresses stride 4 dwords)
// this yields exactly 2 lanes/bank (free).  Phase-2 reads the group as a
// contiguous ds_read_b128 (canonical, conflict-free) and un-rotates in
// registers (8 VALU - VALU pipe has slack; LDS pipe is the scarce one).
// Also: corner POINTERS in LDS (4x ds_read_b64/iter) -> one int4 OFFSET
// read + VALU base-pointer select (32 -> 12 LDS cyc/iter).
//
// New LDS budget ~900 cyc/block (~37us) -> write path becomes the limit.

#define PTS  4
#define ROWF 963   // 3 coords + 960 samples
#define GPP  240   // float4 groups per point

typedef float fx4 __attribute__((ext_vector_type(4)));

// rotation amount for group g
__device__ __forceinline__ int rot_of(int g) { return (g + (g >> 3)) & 3; }

// store logical dword a of the block chunk into swizzled LDS
__device__ __forceinline__ void store1(float* smem, int a, float v) {
    const int g = a >> 2;
    const int e = ((a & 3) + g + (g >> 3)) & 3;   // (a&3 + f(g)) & 3
    smem[(g << 2) | e] = v;
}

__global__ __launch_bounds__(256) void graphproj_kernel(
    const float* __restrict__ coords,
    const float* __restrict__ f1, const float* __restrict__ f2,
    const float* __restrict__ f3, const float* __restrict__ f4,
    float* __restrict__ out, int N)
{
    __shared__ __align__(16) float smem[PTS * ROWF];   // 15408 B, swizzled
    __shared__ __align__(16) float s_w[PTS][4][4];     // w11,w21,w12,w22
    __shared__ __align__(16) int   s_off[PTS][4][4];   // corner float-offsets

    const int b  = blockIdx.x;
    const int t  = threadIdx.x;
    const int p0 = b * PTS;
    const int npts = min(PTS, N - p0);

    // ---- phase 0: weights + corner offsets (16 lanes) ----
    if (t < 4 * npts) {
        const int pt = t >> 2;
        const int lv = t & 3;
        const int p  = p0 + pt;
        const float X = coords[p * 3 + 0];
        const float Y = coords[p * 3 + 1];
        const float Z = coords[p * 3 + 2];
        float h = 250.0f * (-Y) / (-Z) + 112.0f;
        float w = 250.0f * X / (-Z) + 112.0f;
        h = fminf(fmaxf(h, 0.0f), 223.0f);
        w = fminf(fmaxf(w, 0.0f), 223.0f);

        const int H = (lv == 0) ? 56 : (lv == 1) ? 28 : (lv == 2) ? 14 : 7;
        const int C = (lv == 0) ? 64 : (lv == 1) ? 128 : (lv == 2) ? 256 : 512;
        const float scale = (float)H / 224.0f;   // exact power-of-2 ratio
        const float x = h * scale, y = w * scale;
        const float x1f = floorf(x), x2f = fminf(ceilf(x), (float)(H - 1));
        const float y1f = floorf(y), y2f = fminf(ceilf(y), (float)(H - 1));
        const int xi1 = (int)x1f, xi2 = (int)x2f;
        const int yi1 = (int)y1f, yi2 = (int)y2f;

        s_w[pt][lv][0] = (x2f - x) * (y2f - y);   // w11 -> Q11 (xi1,yi1)
        s_w[pt][lv][1] = (x - x1f) * (y2f - y);   // w21 -> Q21 (xi2,yi1)
        s_w[pt][lv][2] = (x2f - x) * (y - y1f);   // w12 -> Q12 (xi1,yi2)
        s_w[pt][lv][3] = (x - x1f) * (y - y1f);   // w22 -> Q22 (xi2,yi2)

        s_off[pt][lv][0] = (xi1 * H + yi1) * C;
        s_off[pt][lv][1] = (xi2 * H + yi1) * C;
        s_off[pt][lv][2] = (xi1 * H + yi2) * C;
        s_off[pt][lv][3] = (xi2 * H + yi2) * C;
    }
    // coords into the (swizzled) LDS chunk (cols 0..2 of each row)
    if (t >= 64 && t < 64 + 3 * npts) {
        const int i = t - 64;
        store1(smem, (i / 3) * ROWF + (i % 3), coords[p0 * 3 + i]);
    }
    __syncthreads();

    if (npts == PTS) {
        // ---- phase 1: gather + blend, swizzled scalar LDS writes ----
        for (int gf = t; gf < PTS * GPP; gf += 256) {
            const int pt = gf / GPP;
            const int g  = gf - pt * GPP;
            // level ranges: [0,16) L1, [16,48) L2, [48,112) L3, [112,240) L4
            const int lv = (g >= 16) + (g >= 48) + (g >= 112);
            const int c4 = g - ((lv == 0) ? 0 : (lv == 1) ? 16 : (lv == 2) ? 48 : 112);

            const float4 wv = *(const float4*)&s_w[pt][lv][0];
            const int4   ov = *(const int4*)&s_off[pt][lv][0];
            const float* base = (lv == 0) ? f1 : (lv == 1) ? f2 : (lv == 2) ? f3 : f4;

            const fx4 a  = ((const fx4*)(base + ov.x))[c4];
            const fx4 bb = ((const fx4*)(base + ov.y))[c4];
            const fx4 c  = ((const fx4*)(base + ov.z))[c4];
            const fx4 d  = ((const fx4*)(base + ov.w))[c4];

            fx4 r;
            r.x = wv.x * a.x + wv.y * bb.x + wv.z * c.x + wv.w * d.x;
            r.y = wv.x * a.y + wv.y * bb.y + wv.z * c.y + wv.w * d.y;
            r.z = wv.x * a.z + wv.y * bb.z + wv.z * c.z + wv.w * d.z;
            r.w = wv.x * a.w + wv.y * bb.w + wv.z * c.w + wv.w * d.w;

            const int L = pt * ROWF + 3 + 4 * g;
            store1(smem, L + 0, r.x);
            store1(smem, L + 1, r.y);
            store1(smem, L + 2, r.z);
            store1(smem, L + 3, r.w);
        }
        __syncthreads();

        // ---- phase 2: b128 reads (conflict-free), register un-rotate,
        //      aligned coalesced nontemporal dwordx4 stores ----
        const fx4* sp  = (const fx4*)smem;
        fx4*       dst = (fx4*)(out + (size_t)p0 * ROWF);
        for (int j = t; j < PTS * ROWF / 4; j += 256) {   // 963 groups
            const fx4 v = sp[j];
            const int r = rot_of(j);
            // out[m] = v[(m + r) & 3]  (rotate-left by r), branch-free selects
            const fx4 t2 = (r & 2) ? (fx4){v.z, v.w, v.x, v.y} : v;
            const fx4 u  = (r & 1) ? (fx4){t2.y, t2.z, t2.w, t2.x} : t2;
            __builtin_nontemporal_store(u, &dst[j]);
        }
    } else {
        // ---- tail block (N % PTS != 0): per-float direct path, no LDS ----
        for (int i = t; i < npts * ROWF; i += 256) {
            const int pt = i / ROWF;
            const int rr = i - pt * ROWF;
            float v;
            if (rr < 3) {
                v = coords[(p0 + pt) * 3 + rr];
            } else {
                const int c  = rr - 3;
                const int lv = (c >= 64) + (c >= 192) + (c >= 448);
                const int cc = c - ((lv == 0) ? 0 : (lv == 1) ? 64 : (lv == 2) ? 192 : 448);
                const float* base = (lv == 0) ? f1 : (lv == 1) ? f2 : (lv == 2) ? f3 : f4;
                v = s_w[pt][lv][0] * base[s_off[pt][lv][0] + cc]
                  + s_w[pt][lv][1] * base[s_off[pt][lv][1] + cc]
                  + s_w[pt][lv][2] * base[s_off[pt][lv][2] + cc]
                  + s_w[pt][lv][3] * base[s_off[pt][lv][3] + cc];
            }
            out[(size_t)p0 * ROWF + i] = v;
        }
    }
}

extern "C" void kernel_launch(void* const* d_in, const int* in_sizes, int n_in,
                              void* d_out, int out_size, void* d_ws, size_t ws_size,
                              hipStream_t stream) {
    const float* coords = (const float*)d_in[0];
    const float* f1 = (const float*)d_in[1];
    const float* f2 = (const float*)d_in[2];
    const float* f3 = (const float*)d_in[3];
    const float* f4 = (const float*)d_in[4];
    float* out = (float*)d_out;
    const int N = in_sizes[0] / 3;

    const int blocks = (N + PTS - 1) / PTS;
    graphproj_kernel<<<blocks, 256, 0, stream>>>(coords, f1, f2, f3, f4, out, N);
}